// Round 1
// baseline (436.359 us; speedup 1.0000x reference)
//
#include <hip/hip_runtime.h>
#include <hip/hip_bf16.h>
#include <stdint.h>

// out = relu(x @ W_up^T) @ W_down^T + x @ W_expert
// (softmax-of-top-k weights sum to 1 -> MoE gating is a mathematical no-op)
//
// M = 4*4096 = 16384 tokens, D = 2048.
// Strategy: bf16 MFMA GEMMs (16x16x32), 128x128 tile, BK=64, 4 waves,
// global_load_lds width=16 with XOR-swizzled LDS (linear dest + pre-swizzled
// global source + swizzled ds_read), XCD-aware block swizzle.
// GEMM2 fuses both output terms via K=4096 concat: A_big=[h|x], B_big=[W_down|W_expert^T].

#define DIM 2048
#define MTOT 16384

typedef unsigned short u16;
typedef __bf16 bf16x8 __attribute__((ext_vector_type(8)));
typedef float f32x4 __attribute__((ext_vector_type(4)));

__device__ __forceinline__ u16 f2bf(float f) {
    union { float f; unsigned int u; } a; a.f = f;
    unsigned int u = a.u;
    unsigned int r = (u + 0x7fffu + ((u >> 16) & 1u)) >> 16;  // RNE
    return (u16)r;
}

__device__ __forceinline__ bf16x8 frag_load(const void* p) {
    union { uint4 u; bf16x8 b; } x;
    x.u = *(const uint4*)p;
    return x.b;
}

// ---------------------------------------------------------------------------
// Conversion: fp32 -> bf16 with row re-stride (src rows are 2048 wide).
// dst[row*dld + doff + col] = bf16(src[row*2048 + col])
__global__ void cvt_pack(const float* __restrict__ src, u16* __restrict__ dst,
                         long n4, int dld, int doff) {
    long i = (long)blockIdx.x * blockDim.x + threadIdx.x;
    long stride = (long)gridDim.x * blockDim.x;
    for (; i < n4; i += stride) {
        long e = i << 2;
        long row = e >> 11;          // / 2048
        int col = (int)(e & 2047);
        float4 v = *(const float4*)(src + e);
        union { u16 q[4]; uint2 d; } u;
        u.q[0] = f2bf(v.x); u.q[1] = f2bf(v.y);
        u.q[2] = f2bf(v.z); u.q[3] = f2bf(v.w);
        *(uint2*)(dst + row * (long)dld + doff + col) = u.d;
    }
}

// W_expert is [K,N] applied as x @ W_expert; we need B^T layout [N,K].
// 32x32 LDS tile transpose; writes into B_big columns 2048..4095.
__global__ void cvt_transpose(const float* __restrict__ W, u16* __restrict__ dst) {
    __shared__ float t[32][33];
    int bx = blockIdx.x & 63;    // tile along n (cols of W)
    int by = blockIdx.x >> 6;    // tile along k (rows of W)
    int x = threadIdx.x & 31, y = threadIdx.x >> 5;
    #pragma unroll
    for (int j = 0; j < 32; j += 8)
        t[y + j][x] = W[(size_t)(by * 32 + y + j) * 2048 + bx * 32 + x];
    __syncthreads();
    #pragma unroll
    for (int j = 0; j < 32; j += 8)
        dst[(size_t)(bx * 32 + y + j) * 4096 + 2048 + by * 32 + x] = f2bf(t[x][y + j]);
}

// ---------------------------------------------------------------------------
// bf16 GEMM, C[M,N] = A[M,K] @ B[N,K]^T  (B given transposed, row-major [N,K])
// BM=BN=128, BK=64, 256 threads (4 waves in 2x2), each wave does 64x64 via
// 4x4 grid of 16x16x32 MFMA fragments.
// LDS tiles [128 rows][64 bf16 = 128 B] with XOR swizzle:
//   element (r,c) at byte r*128 + ((2c) ^ ((r&7)<<4))
// global_load_lds writes linearly -> global source address pre-swizzled.
// MODE 0: C = relu(acc) -> bf16, ldc=4096 (h into A_big left half)
// MODE 1: C = acc -> fp32, ldc=2048 (d_out)
template <int MODE>
__global__ __launch_bounds__(256, 2)
void gemm_bt(const u16* __restrict__ A, const u16* __restrict__ B,
             void* __restrict__ Cptr, int lda, int ldb, int K) {
    __shared__ u16 ldsA[128 * 64];
    __shared__ u16 ldsB[128 * 64];

    const int tid  = threadIdx.x;
    const int lane = tid & 63;
    const int wv   = tid >> 6;
    const int wr   = wv >> 1;   // wave row (0..1)
    const int wc   = wv & 1;    // wave col (0..1)

    // XCD-aware bijective swizzle (grid=2048, divisible by 8)
    int bid = blockIdx.x;
    int cpx = gridDim.x >> 3;
    int swz = (bid & 7) * cpx + (bid >> 3);
    int tile_n = swz & 15;      // N/128 = 16
    int tile_m = swz >> 4;

    const int rowA0 = tile_m * 128;
    const int rowB0 = tile_n * 128;

    // Staging geometry: step s covers bytes [s*4096, s*4096+4096); thread tid
    // writes linear LDS bytes o = s*4096 + tid*16.
    //   r = o>>7 = s*32 + (tid>>3)
    //   swizzled source column cb = ((tid&7)<<4) ^ (((tid>>3)&7)<<4)
    const int r_base = tid >> 3;
    const int c_elt  = (((tid & 7) ^ ((tid >> 3) & 7)) << 3);  // bf16 units
    const u16* pA[4];
    const u16* pB[4];
    int stg_off[4];
    #pragma unroll
    for (int s = 0; s < 4; ++s) {
        int r = s * 32 + r_base;
        pA[s] = A + (size_t)(rowA0 + r) * lda + c_elt;
        pB[s] = B + (size_t)(rowB0 + r) * ldb + c_elt;
        stg_off[s] = s * 4096 + (wv << 10);   // wave-uniform byte offset
    }

    f32x4 acc[4][4];
    #pragma unroll
    for (int m = 0; m < 4; ++m)
        #pragma unroll
        for (int n = 0; n < 4; ++n)
            acc[m][n] = (f32x4){0.f, 0.f, 0.f, 0.f};

    const char* cA = (const char*)ldsA;
    const char* cB = (const char*)ldsB;
    const int nK = K >> 6;

    for (int kt = 0; kt < nK; ++kt) {
        const int k0 = kt << 6;
        #pragma unroll
        for (int s = 0; s < 4; ++s) {
            __builtin_amdgcn_global_load_lds(
                (const __attribute__((address_space(1))) void*)(pA[s] + k0),
                (__attribute__((address_space(3))) void*)((char*)ldsA + stg_off[s]),
                16, 0, 0);
            __builtin_amdgcn_global_load_lds(
                (const __attribute__((address_space(1))) void*)(pB[s] + k0),
                (__attribute__((address_space(3))) void*)((char*)ldsB + stg_off[s]),
                16, 0, 0);
        }
        __syncthreads();

        #pragma unroll
        for (int kk = 0; kk < 2; ++kk) {
            const int kb = (kk << 6) + ((lane >> 4) << 4);  // byte offset of k-part
            bf16x8 av[4], bv[4];
            #pragma unroll
            for (int i = 0; i < 4; ++i) {
                int ra = (wr << 6) + (i << 4) + (lane & 15);
                av[i] = frag_load(cA + (ra << 7) + (kb ^ ((ra & 7) << 4)));
                int rb = (wc << 6) + (i << 4) + (lane & 15);
                bv[i] = frag_load(cB + (rb << 7) + (kb ^ ((rb & 7) << 4)));
            }
            #pragma unroll
            for (int m = 0; m < 4; ++m)
                #pragma unroll
                for (int n = 0; n < 4; ++n)
                    acc[m][n] = __builtin_amdgcn_mfma_f32_16x16x32_bf16(
                        av[m], bv[n], acc[m][n], 0, 0, 0);
        }
        __syncthreads();
    }

    // Epilogue. C/D layout: col = lane&15, row = (lane>>4)*4 + reg.
    const int row0 = tile_m * 128 + (wr << 6) + ((lane >> 4) << 2);
    const int col0 = tile_n * 128 + (wc << 6) + (lane & 15);
    if (MODE == 0) {
        u16* C = (u16*)Cptr;   // ldc = 4096 (left half of A_big)
        #pragma unroll
        for (int m = 0; m < 4; ++m)
            #pragma unroll
            for (int r = 0; r < 4; ++r) {
                size_t base = (size_t)(row0 + m * 16 + r) * 4096;
                #pragma unroll
                for (int n = 0; n < 4; ++n)
                    C[base + col0 + n * 16] = f2bf(fmaxf(acc[m][n][r], 0.f));
            }
    } else {
        float* C = (float*)Cptr;  // ldc = 2048
        #pragma unroll
        for (int m = 0; m < 4; ++m)
            #pragma unroll
            for (int r = 0; r < 4; ++r) {
                size_t base = (size_t)(row0 + m * 16 + r) * 2048;
                #pragma unroll
                for (int n = 0; n < 4; ++n)
                    C[base + col0 + n * 16] = acc[m][n][r];
            }
    }
}

// ---------------------------------------------------------------------------
extern "C" void kernel_launch(void* const* d_in, const int* in_sizes, int n_in,
                              void* d_out, int out_size, void* d_ws, size_t ws_size,
                              hipStream_t stream) {
    const float* x        = (const float*)d_in[0];
    const float* W_up     = (const float*)d_in[1];
    const float* W_down   = (const float*)d_in[2];
    // d_in[3] = W_gate: unused (softmax over top-k sums to 1 -> gating no-op)
    const float* W_expert = (const float*)d_in[4];

    // Workspace layout (bf16 as u16):
    //   A_big [16384][4096] : cols 0..2047 = h (written by GEMM1), 2048..4095 = x
    //   B_big [2048][4096]  : cols 0..2047 = W_down, 2048..4095 = W_expert^T
    //   W_up_bf [2048][2048]
    u16* Abig = (u16*)d_ws;
    u16* Bbig = Abig + (size_t)MTOT * 4096;
    u16* Wup  = Bbig + (size_t)DIM * 4096;
    // total = 159,383,552 bytes

    // x -> bf16 into A_big right half
    cvt_pack<<<2048, 256, 0, stream>>>(x, Abig, (long)MTOT * DIM / 4, 4096, 2048);
    // W_up ([out,in] = [N,K] already) -> bf16
    cvt_pack<<<1024, 256, 0, stream>>>(W_up, Wup, (long)DIM * DIM / 4, 2048, 0);
    // W_down -> B_big left half
    cvt_pack<<<1024, 256, 0, stream>>>(W_down, Bbig, (long)DIM * DIM / 4, 4096, 0);
    // W_expert^T -> B_big right half
    cvt_transpose<<<4096, 256, 0, stream>>>(W_expert, Bbig);

    // GEMM1: h = relu(x @ W_up^T) -> bf16 into A_big left half
    gemm_bt<0><<<2048, 256, 0, stream>>>(Abig + 2048, Wup, Abig, 4096, 2048, 2048);
    // GEMM2: out = A_big @ B_big^T = h @ W_down^T + x @ W_expert  (fp32)
    gemm_bt<1><<<2048, 256, 0, stream>>>(Abig, Bbig, d_out, 4096, 4096, 4096);
}

// Round 2
// 411.785 us; speedup vs baseline: 1.0597x; 1.0597x over previous
//
#include <hip/hip_runtime.h>
#include <hip/hip_bf16.h>
#include <stdint.h>

// out = relu(x @ W_up^T) @ W_down^T + x @ W_expert
// (softmax-of-top-k weights sum to 1 -> MoE gating is a mathematical no-op)
//
// 256x256-tile 8-phase bf16 MFMA GEMM (m201-style): BK=64, 512 threads (8 waves
// 2Mx4N), per-wave output 128x64 split as 2x2 C-quadrants of the BLOCK tile so
// every phase reads exactly one A-half + one B-half. Depth-1 half-granular
// prefetch with counted vmcnt (never 0 in the loop), raw s_barrier, setprio
// around MFMA clusters, XOR-swizzled LDS (linear global_load_lds dest +
// pre-swizzled source + swizzled ds_read) -> 0 bank conflicts.

#define DIM 2048
#define MTOT 16384

typedef unsigned short u16;
typedef __bf16 bf16x8 __attribute__((ext_vector_type(8)));
typedef float f32x4 __attribute__((ext_vector_type(4)));

__device__ __forceinline__ u16 f2bf(float f) {
    union { float f; unsigned int u; } a; a.f = f;
    unsigned int u = a.u;
    unsigned int r = (u + 0x7fffu + ((u >> 16) & 1u)) >> 16;  // RNE
    return (u16)r;
}

__device__ __forceinline__ bf16x8 frag_load(const void* p) {
    union { uint4 u; bf16x8 b; } x;
    x.u = *(const uint4*)p;
    return x.b;
}

// ---------------------------------------------------------------------------
// fp32 -> bf16 with row re-stride (src rows are 2048 wide).
__global__ void cvt_pack(const float* __restrict__ src, u16* __restrict__ dst,
                         long n4, int dld, int doff) {
    long i = (long)blockIdx.x * blockDim.x + threadIdx.x;
    long stride = (long)gridDim.x * blockDim.x;
    for (; i < n4; i += stride) {
        long e = i << 2;
        long row = e >> 11;
        int col = (int)(e & 2047);
        float4 v = *(const float4*)(src + e);
        union { u16 q[4]; uint2 d; } u;
        u.q[0] = f2bf(v.x); u.q[1] = f2bf(v.y);
        u.q[2] = f2bf(v.z); u.q[3] = f2bf(v.w);
        *(uint2*)(dst + row * (long)dld + doff + col) = u.d;
    }
}

// W_expert is [K,N] applied as x @ W_expert; need B^T layout [N,K] into B_big
// columns 2048..4095.
__global__ void cvt_transpose(const float* __restrict__ W, u16* __restrict__ dst) {
    __shared__ float t[32][33];
    int bx = blockIdx.x & 63;
    int by = blockIdx.x >> 6;
    int x = threadIdx.x & 31, y = threadIdx.x >> 5;
    #pragma unroll
    for (int j = 0; j < 32; j += 8)
        t[y + j][x] = W[(size_t)(by * 32 + y + j) * 2048 + bx * 32 + x];
    __syncthreads();
    #pragma unroll
    for (int j = 0; j < 32; j += 8)
        dst[(size_t)(bx * 32 + y + j) * 4096 + 2048 + by * 32 + x] = f2bf(t[x][y + j]);
}

// ---------------------------------------------------------------------------
// 256^2 8-phase GEMM: C[M,N] = A[M,K] @ B[N,K]^T.
// LDS per buffer: A halves (2 x 128rows x 64cols bf16 = 2 x 16KB) at 0,
//                 B halves at 32768. Two buffers -> 128 KiB.
// Swizzle: element (r,c) of a half at byte r*128 + ((2c) ^ ((r&7)<<4)).
// Half issue order: H1=A0, H2=B0, H3=B1, H4=A1.
// Quadrant order:  P1=(0,0) P2=(0,1) P3=(1,1) P4=(1,0).
template <int MODE>
__global__ __launch_bounds__(512, 2)
void gemm256(const u16* __restrict__ A, const u16* __restrict__ B,
             void* __restrict__ Cptr, int lda, int ldb, int K) {
    __shared__ char lds[2][65536];

    const int tid  = threadIdx.x;
    const int lane = tid & 63;
    const int wv   = tid >> 6;   // 0..7
    const int wr   = wv >> 2;    // 0..1  (M half within a quadrant: rows wr*64)
    const int wc   = wv & 3;     // 0..3  (N strip within a quadrant: cols wc*32)

    // XCD-aware bijective swizzle (grid=512, divisible by 8)
    int bid = blockIdx.x;
    int cpx = gridDim.x >> 3;
    int swz = (bid & 7) * cpx + (bid >> 3);
    int tile_n = swz & 7;        // N/256 = 8
    int tile_m = swz >> 3;       // M/256 = 64

    const int rowA0 = tile_m * 256;
    const int rowB0 = tile_n * 256;

    // Staging: per half 2 loads/thread. Load j, thread tid writes linear LDS
    // byte j*8192 + tid*16 -> row r = j*64 + (tid>>3), linear col (tid&7)*16.
    // Pre-swizzled source column (r&7 == (tid>>3)&7):
    const int r_sub = tid >> 3;
    const int c_src = ((tid & 7) ^ (r_sub & 7)) << 3;  // element offset
    const u16* pAb = A + (size_t)(rowA0 + r_sub) * lda + c_src;
    const u16* pBb = B + (size_t)(rowB0 + r_sub) * ldb + c_src;

    f32x4 acc[2][2][4][2];
    #pragma unroll
    for (int a = 0; a < 2; ++a)
        #pragma unroll
        for (int b = 0; b < 2; ++b)
            #pragma unroll
            for (int m = 0; m < 4; ++m)
                #pragma unroll
                for (int n = 0; n < 2; ++n)
                    acc[a][b][m][n] = (f32x4){0.f, 0.f, 0.f, 0.f};

    bf16x8 av[4][2];   // current mh's A fragments (4 m x 2 kk)
    bf16x8 bv[2][2];   // current nh's B fragments (2 n x 2 kk)
    const int kA = (lane >> 4) << 4;   // byte base of k-part, kk=0

#define STAGE_A(H, KOFF, BUF) do {                                              \
    const u16* _s = pAb + (size_t)((H) * 128) * lda + (KOFF);                   \
    __builtin_amdgcn_global_load_lds(                                           \
        (const __attribute__((address_space(1))) void*)_s,                      \
        (__attribute__((address_space(3))) void*)((char*)lds[BUF] + (H)*16384 + (wv<<10)), \
        16, 0, 0);                                                              \
    __builtin_amdgcn_global_load_lds(                                           \
        (const __attribute__((address_space(1))) void*)(_s + (size_t)64 * lda), \
        (__attribute__((address_space(3))) void*)((char*)lds[BUF] + (H)*16384 + 8192 + (wv<<10)), \
        16, 0, 0);                                                              \
  } while (0)

#define STAGE_B(H, KOFF, BUF) do {                                              \
    const u16* _s = pBb + (size_t)((H) * 128) * ldb + (KOFF);                   \
    __builtin_amdgcn_global_load_lds(                                           \
        (const __attribute__((address_space(1))) void*)_s,                      \
        (__attribute__((address_space(3))) void*)((char*)lds[BUF] + 32768 + (H)*16384 + (wv<<10)), \
        16, 0, 0);                                                              \
    __builtin_amdgcn_global_load_lds(                                           \
        (const __attribute__((address_space(1))) void*)(_s + (size_t)64 * ldb), \
        (__attribute__((address_space(3))) void*)((char*)lds[BUF] + 32768 + (H)*16384 + 8192 + (wv<<10)), \
        16, 0, 0);                                                              \
  } while (0)

#define DSREAD_A(MH, CUR) do {                                                  \
    _Pragma("unroll")                                                           \
    for (int m = 0; m < 4; ++m) {                                               \
        int ra = (wr << 6) + (m << 4) + (lane & 15);                            \
        const char* _b = (const char*)lds[CUR] + (MH)*16384 + (ra << 7);        \
        int sw = (ra & 7) << 4;                                                 \
        av[m][0] = frag_load(_b + (kA ^ sw));                                   \
        av[m][1] = frag_load(_b + ((64 + kA) ^ sw));                            \
    } } while (0)

#define DSREAD_B(NH, CUR) do {                                                  \
    _Pragma("unroll")                                                           \
    for (int n = 0; n < 2; ++n) {                                               \
        int rb = (wc << 5) + (n << 4) + (lane & 15);                            \
        const char* _b = (const char*)lds[CUR] + 32768 + (NH)*16384 + (rb << 7);\
        int sw = (rb & 7) << 4;                                                 \
        bv[n][0] = frag_load(_b + (kA ^ sw));                                   \
        bv[n][1] = frag_load(_b + ((64 + kA) ^ sw));                            \
    } } while (0)

#define MFMA_Q(MH, NH) do {                                                     \
    __builtin_amdgcn_s_setprio(1);                                              \
    _Pragma("unroll")                                                           \
    for (int m = 0; m < 4; ++m)                                                 \
        _Pragma("unroll")                                                       \
        for (int n = 0; n < 2; ++n) {                                           \
            acc[MH][NH][m][n] = __builtin_amdgcn_mfma_f32_16x16x32_bf16(        \
                av[m][0], bv[n][0], acc[MH][NH][m][n], 0, 0, 0);                \
            acc[MH][NH][m][n] = __builtin_amdgcn_mfma_f32_16x16x32_bf16(        \
                av[m][1], bv[n][1], acc[MH][NH][m][n], 0, 0, 0);                \
        }                                                                       \
    __builtin_amdgcn_s_setprio(0);                                              \
  } while (0)

#define WAIT_VM(N) asm volatile("s_waitcnt vmcnt(" #N ")" ::: "memory")
#define WAIT_LGKM() do {                                                        \
    asm volatile("s_waitcnt lgkmcnt(0)" ::: "memory");                          \
    __builtin_amdgcn_sched_barrier(0);                                          \
  } while (0)
#define BAR() __builtin_amdgcn_s_barrier()

    // Prologue: stage tile 0 (H1..H4), guarantee A0,B0 before P1 reads them.
    STAGE_A(0, 0, 0);
    STAGE_B(0, 0, 0);
    STAGE_B(1, 0, 0);
    STAGE_A(1, 0, 0);
    WAIT_VM(4);
    BAR();

    const int nK = K >> 6;
    int cur = 0;
    for (int t = 0; t < nK - 1; ++t) {
        const int koff = (t + 1) << 6;
        const int nxt = cur ^ 1;
        // P1: Q(0,0) — needs A0,B0 (guaranteed by prev P4 wait+bar)
        DSREAD_A(0, cur); DSREAD_B(0, cur);
        STAGE_A(0, koff, nxt);                 // t+1:H1
        WAIT_VM(4); BAR(); WAIT_LGKM();
        MFMA_Q(0, 0);
        BAR();
        // P2: Q(0,1) — A reused, needs B1 (guaranteed by P1 wait+bar)
        DSREAD_B(1, cur);
        STAGE_B(0, koff, nxt);                 // t+1:H2
        WAIT_VM(4); BAR(); WAIT_LGKM();
        MFMA_Q(0, 1);
        BAR();
        // P3: Q(1,1) — B reused, needs A1 (guaranteed by P2 wait+bar)
        DSREAD_A(1, cur);
        STAGE_B(1, koff, nxt);                 // t+1:H3
        WAIT_VM(6); BAR(); WAIT_LGKM();
        MFMA_Q(1, 1);
        BAR();
        // P4: Q(1,0) — A reused, B0 re-read (landed long ago)
        DSREAD_B(0, cur);
        STAGE_A(1, koff, nxt);                 // t+1:H4
        WAIT_VM(4); BAR(); WAIT_LGKM();        // protects next-iter P1 (A0,B0)
        MFMA_Q(1, 0);
        BAR();
        cur = nxt;
    }

    // Last tile: no prefetch; drain 2 -> 0.
    DSREAD_A(0, cur); DSREAD_B(0, cur);
    WAIT_VM(2); BAR(); WAIT_LGKM();
    MFMA_Q(0, 0);
    DSREAD_B(1, cur);
    WAIT_VM(0); BAR(); WAIT_LGKM();
    MFMA_Q(0, 1);
    DSREAD_A(1, cur);
    WAIT_LGKM();
    MFMA_Q(1, 1);
    DSREAD_B(0, cur);
    WAIT_LGKM();
    MFMA_Q(1, 0);

    // Epilogue. C/D layout: col = lane&15, row = (lane>>4)*4 + reg.
    #pragma unroll
    for (int mh = 0; mh < 2; ++mh)
        #pragma unroll
        for (int m = 0; m < 4; ++m)
            #pragma unroll
            for (int r = 0; r < 4; ++r) {
                int row = rowA0 + mh * 128 + (wr << 6) + (m << 4) + ((lane >> 4) << 2) + r;
                #pragma unroll
                for (int nh = 0; nh < 2; ++nh)
                    #pragma unroll
                    for (int n = 0; n < 2; ++n) {
                        int col = tile_n * 256 + nh * 128 + (wc << 5) + (n << 4) + (lane & 15);
                        float v = acc[mh][nh][m][n][r];
                        if (MODE == 0) {
                            ((u16*)Cptr)[(size_t)row * 4096 + col] = f2bf(fmaxf(v, 0.f));
                        } else {
                            ((float*)Cptr)[(size_t)row * 2048 + col] = v;
                        }
                    }
            }
#undef STAGE_A
#undef STAGE_B
#undef DSREAD_A
#undef DSREAD_B
#undef MFMA_Q
#undef WAIT_VM
#undef WAIT_LGKM
#undef BAR
}

// ---------------------------------------------------------------------------
extern "C" void kernel_launch(void* const* d_in, const int* in_sizes, int n_in,
                              void* d_out, int out_size, void* d_ws, size_t ws_size,
                              hipStream_t stream) {
    const float* x        = (const float*)d_in[0];
    const float* W_up     = (const float*)d_in[1];
    const float* W_down   = (const float*)d_in[2];
    // d_in[3] = W_gate: unused (softmax over top-k sums to 1 -> gating no-op)
    const float* W_expert = (const float*)d_in[4];

    // Workspace (bf16 as u16):
    //   A_big [16384][4096]: cols 0..2047 = h (GEMM1 output), 2048..4095 = x
    //   B_big [2048][4096] : cols 0..2047 = W_down, 2048..4095 = W_expert^T
    //   W_up_bf [2048][2048]
    u16* Abig = (u16*)d_ws;
    u16* Bbig = Abig + (size_t)MTOT * 4096;
    u16* Wup  = Bbig + (size_t)DIM * 4096;

    cvt_pack<<<2048, 256, 0, stream>>>(x, Abig, (long)MTOT * DIM / 4, 4096, 2048);
    cvt_pack<<<1024, 256, 0, stream>>>(W_up, Wup, (long)DIM * DIM / 4, 2048, 0);
    cvt_pack<<<1024, 256, 0, stream>>>(W_down, Bbig, (long)DIM * DIM / 4, 4096, 0);
    cvt_transpose<<<4096, 256, 0, stream>>>(W_expert, Bbig);

    // GEMM1: h = relu(x @ W_up^T) -> bf16 into A_big left half
    gemm256<0><<<512, 512, 0, stream>>>(Abig + 2048, Wup, Abig, 4096, 2048, 2048);
    // GEMM2: out = A_big @ B_big^T = h @ W_down^T + x @ W_expert (fp32)
    gemm256<1><<<512, 512, 0, stream>>>(Abig, Bbig, d_out, 4096, 4096, 4096);
}

// Round 3
// 369.212 us; speedup vs baseline: 1.1819x; 1.1153x over previous
//
#include <hip/hip_runtime.h>
#include <hip/hip_bf16.h>
#include <stdint.h>

// out = relu(x @ W_up^T) @ W_down^T + x @ W_expert
// (softmax-of-top-k weights sum to 1 -> MoE gating is a mathematical no-op)
//
// 256x256-tile bf16 MFMA GEMM, BK=64, 512 threads (8 waves 2Mx4N).
// 2-sync-per-K-tile schedule: two fused regions per tile, each
// {ds_reads + stage-next + MFMA cluster}, with counted vmcnt + raw s_barrier
// only at the two region boundaries. B fragments (both halves) persist in
// registers for the whole K-tile -> 24 ds_read_b128 / tile / wave.
// XOR-swizzled LDS (linear global_load_lds dest + pre-swizzled source +
// swizzled ds_read) -> 0 bank conflicts.

#define DIM 2048
#define MTOT 16384

typedef unsigned short u16;
typedef __bf16 bf16x8 __attribute__((ext_vector_type(8)));
typedef float f32x4 __attribute__((ext_vector_type(4)));

__device__ __forceinline__ u16 f2bf(float f) {
    union { float f; unsigned int u; } a; a.f = f;
    unsigned int u = a.u;
    unsigned int r = (u + 0x7fffu + ((u >> 16) & 1u)) >> 16;  // RNE
    return (u16)r;
}

__device__ __forceinline__ bf16x8 frag_load(const void* p) {
    union { uint4 u; bf16x8 b; } x;
    x.u = *(const uint4*)p;
    return x.b;
}

// ---------------------------------------------------------------------------
// fp32 -> bf16 with row re-stride (src rows are 2048 wide).
__global__ void cvt_pack(const float* __restrict__ src, u16* __restrict__ dst,
                         long n4, int dld, int doff) {
    long i = (long)blockIdx.x * blockDim.x + threadIdx.x;
    long stride = (long)gridDim.x * blockDim.x;
    for (; i < n4; i += stride) {
        long e = i << 2;
        long row = e >> 11;
        int col = (int)(e & 2047);
        float4 v = *(const float4*)(src + e);
        union { u16 q[4]; uint2 d; } u;
        u.q[0] = f2bf(v.x); u.q[1] = f2bf(v.y);
        u.q[2] = f2bf(v.z); u.q[3] = f2bf(v.w);
        *(uint2*)(dst + row * (long)dld + doff + col) = u.d;
    }
}

// W_expert is [K,N] applied as x @ W_expert; need B^T layout [N,K] into B_big
// columns 2048..4095.
__global__ void cvt_transpose(const float* __restrict__ W, u16* __restrict__ dst) {
    __shared__ float t[32][33];
    int bx = blockIdx.x & 63;
    int by = blockIdx.x >> 6;
    int x = threadIdx.x & 31, y = threadIdx.x >> 5;
    #pragma unroll
    for (int j = 0; j < 32; j += 8)
        t[y + j][x] = W[(size_t)(by * 32 + y + j) * 2048 + bx * 32 + x];
    __syncthreads();
    #pragma unroll
    for (int j = 0; j < 32; j += 8)
        dst[(size_t)(bx * 32 + y + j) * 4096 + 2048 + by * 32 + x] = f2bf(t[x][y + j]);
}

// ---------------------------------------------------------------------------
// 256^2 GEMM: C[M,N] = A[M,K] @ B[N,K]^T.
// LDS per buffer: A halves (2 x 128rows x 128B) at 0, B halves at 32768.
// Two buffers -> 128 KiB. Swizzle: (r,c) at byte r*128 + ((2c) ^ ((r&7)<<4)).
// Stage order per tile: A0, B0 (region 1), B1, A1 (region 2).
// Sync invariant: entering tile t, exactly t's A1 (2 loads) is in flight.
//   mid-sync:  in-flight = {A1^t, A0^{t+1}, B0^{t+1}} = 6 -> vmcnt(4) retires A1^t
//   end-sync:  in-flight = 8 (t+1 halves)             -> vmcnt(2) retires A0,B0,B1
template <int MODE>
__global__ __launch_bounds__(512, 2)
void gemm256(const u16* __restrict__ A, const u16* __restrict__ B,
             void* __restrict__ Cptr, int lda, int ldb, int K) {
    __shared__ char lds[2][65536];

    const int tid  = threadIdx.x;
    const int lane = tid & 63;
    const int wv   = tid >> 6;   // 0..7
    const int wr   = wv >> 2;    // 0..1  (M half within a quadrant: rows wr*64)
    const int wc   = wv & 3;     // 0..3  (N strip within a quadrant: cols wc*32)

    // XCD-aware bijective swizzle (grid=512, divisible by 8)
    int bid = blockIdx.x;
    int cpx = gridDim.x >> 3;
    int swz = (bid & 7) * cpx + (bid >> 3);
    int tile_n = swz & 7;        // N/256 = 8
    int tile_m = swz >> 3;       // M/256 = 64

    const int rowA0 = tile_m * 256;
    const int rowB0 = tile_n * 256;

    // Staging: per half 2 loads/thread. Load j: linear LDS byte j*8192+tid*16
    // -> row r = j*64 + (tid>>3), linear col (tid&7)*16. Pre-swizzled source:
    const int r_sub = tid >> 3;
    const int c_src = ((tid & 7) ^ (r_sub & 7)) << 3;  // element offset
    const u16* pAb = A + (size_t)(rowA0 + r_sub) * lda + c_src;
    const u16* pBb = B + (size_t)(rowB0 + r_sub) * ldb + c_src;

    f32x4 acc[2][2][4][2];
    #pragma unroll
    for (int a = 0; a < 2; ++a)
        #pragma unroll
        for (int b = 0; b < 2; ++b)
            #pragma unroll
            for (int m = 0; m < 4; ++m)
                #pragma unroll
                for (int n = 0; n < 2; ++n)
                    acc[a][b][m][n] = (f32x4){0.f, 0.f, 0.f, 0.f};

    bf16x8 av[4][2];    // current A half's fragments (4 m x 2 kk)
    bf16x8 bva[2][2];   // B half 0 fragments, live all tile
    bf16x8 bvb[2][2];   // B half 1 fragments, live all tile
    const int kA = (lane >> 4) << 4;   // byte base of k-part, kk=0

#define STAGE_A(H, KOFF, BUF) do {                                              \
    const u16* _s = pAb + (size_t)((H) * 128) * lda + (KOFF);                   \
    __builtin_amdgcn_global_load_lds(                                           \
        (const __attribute__((address_space(1))) void*)_s,                      \
        (__attribute__((address_space(3))) void*)((char*)lds[BUF] + (H)*16384 + (wv<<10)), \
        16, 0, 0);                                                              \
    __builtin_amdgcn_global_load_lds(                                           \
        (const __attribute__((address_space(1))) void*)(_s + (size_t)64 * lda), \
        (__attribute__((address_space(3))) void*)((char*)lds[BUF] + (H)*16384 + 8192 + (wv<<10)), \
        16, 0, 0);                                                              \
  } while (0)

#define STAGE_B(H, KOFF, BUF) do {                                              \
    const u16* _s = pBb + (size_t)((H) * 128) * ldb + (KOFF);                   \
    __builtin_amdgcn_global_load_lds(                                           \
        (const __attribute__((address_space(1))) void*)_s,                      \
        (__attribute__((address_space(3))) void*)((char*)lds[BUF] + 32768 + (H)*16384 + (wv<<10)), \
        16, 0, 0);                                                              \
    __builtin_amdgcn_global_load_lds(                                           \
        (const __attribute__((address_space(1))) void*)(_s + (size_t)64 * ldb), \
        (__attribute__((address_space(3))) void*)((char*)lds[BUF] + 32768 + (H)*16384 + 8192 + (wv<<10)), \
        16, 0, 0);                                                              \
  } while (0)

#define DSREAD_A(MH, CUR) do {                                                  \
    _Pragma("unroll")                                                           \
    for (int m = 0; m < 4; ++m) {                                               \
        int ra = (wr << 6) + (m << 4) + (lane & 15);                            \
        const char* _b = (const char*)lds[CUR] + (MH)*16384 + (ra << 7);        \
        int sw = (ra & 7) << 4;                                                 \
        av[m][0] = frag_load(_b + (kA ^ sw));                                   \
        av[m][1] = frag_load(_b + ((64 + kA) ^ sw));                            \
    } } while (0)

#define DSREAD_B(NH, CUR, DST) do {                                             \
    _Pragma("unroll")                                                           \
    for (int n = 0; n < 2; ++n) {                                               \
        int rb = (wc << 5) + (n << 4) + (lane & 15);                            \
        const char* _b = (const char*)lds[CUR] + 32768 + (NH)*16384 + (rb << 7);\
        int sw = (rb & 7) << 4;                                                 \
        DST[n][0] = frag_load(_b + (kA ^ sw));                                  \
        DST[n][1] = frag_load(_b + ((64 + kA) ^ sw));                           \
    } } while (0)

#define MFMA_Q(MH, NH, BV) do {                                                 \
    __builtin_amdgcn_s_setprio(1);                                              \
    _Pragma("unroll")                                                           \
    for (int m = 0; m < 4; ++m)                                                 \
        _Pragma("unroll")                                                       \
        for (int n = 0; n < 2; ++n) {                                           \
            acc[MH][NH][m][n] = __builtin_amdgcn_mfma_f32_16x16x32_bf16(        \
                av[m][0], BV[n][0], acc[MH][NH][m][n], 0, 0, 0);                \
            acc[MH][NH][m][n] = __builtin_amdgcn_mfma_f32_16x16x32_bf16(        \
                av[m][1], BV[n][1], acc[MH][NH][m][n], 0, 0, 0);                \
        }                                                                       \
    __builtin_amdgcn_s_setprio(0);                                              \
  } while (0)

#define WAIT_VM(N) asm volatile("s_waitcnt vmcnt(" #N ")" ::: "memory")
#define WAIT_LGKM0() asm volatile("s_waitcnt lgkmcnt(0)" ::: "memory")
#define BAR() __builtin_amdgcn_s_barrier()

    // Prologue: stage tile 0 in order A0,B0,B1,A1; guarantee all but A1.
    STAGE_A(0, 0, 0);
    STAGE_B(0, 0, 0);
    STAGE_B(1, 0, 0);
    STAGE_A(1, 0, 0);
    WAIT_VM(2);
    BAR();

    const int nK = K >> 6;
    int cur = 0;
    for (int t = 0; t < nK - 1; ++t) {
        const int koff = (t + 1) << 6;
        const int nxt = cur ^ 1;
        // ---- Region 1: Q00, Q01 (A0 x {B0,B1}) ----
        DSREAD_B(0, cur, bva);
        DSREAD_B(1, cur, bvb);
        DSREAD_A(0, cur);
        STAGE_A(0, koff, nxt);
        STAGE_B(0, koff, nxt);
        MFMA_Q(0, 0, bva);
        MFMA_Q(0, 1, bvb);
        // mid-sync: retire A1^t (in-flight = 6 -> vmcnt(4))
        WAIT_LGKM0();
        WAIT_VM(4);
        BAR();
        // ---- Region 2: Q11, Q10 (A1 x {B1,B0}) ----
        DSREAD_A(1, cur);
        STAGE_B(1, koff, nxt);
        STAGE_A(1, koff, nxt);
        MFMA_Q(1, 1, bvb);
        MFMA_Q(1, 0, bva);
        // end-sync: retire A0,B0,B1 of t+1 (in-flight = 8 -> vmcnt(2))
        WAIT_LGKM0();
        WAIT_VM(2);
        BAR();
        cur = nxt;
    }

    // Last tile (no prefetch). Entering: only this tile's A1 in flight.
    DSREAD_B(0, cur, bva);
    DSREAD_B(1, cur, bvb);
    DSREAD_A(0, cur);
    MFMA_Q(0, 0, bva);
    MFMA_Q(0, 1, bvb);
    WAIT_LGKM0();
    WAIT_VM(0);
    BAR();
    DSREAD_A(1, cur);
    MFMA_Q(1, 1, bvb);
    MFMA_Q(1, 0, bva);

    // Epilogue. C/D layout: col = lane&15, row = (lane>>4)*4 + reg.
    #pragma unroll
    for (int mh = 0; mh < 2; ++mh)
        #pragma unroll
        for (int m = 0; m < 4; ++m)
            #pragma unroll
            for (int r = 0; r < 4; ++r) {
                int row = rowA0 + mh * 128 + (wr << 6) + (m << 4) + ((lane >> 4) << 2) + r;
                #pragma unroll
                for (int nh = 0; nh < 2; ++nh)
                    #pragma unroll
                    for (int n = 0; n < 2; ++n) {
                        int col = tile_n * 256 + nh * 128 + (wc << 5) + (n << 4) + (lane & 15);
                        float v = acc[mh][nh][m][n][r];
                        if (MODE == 0) {
                            ((u16*)Cptr)[(size_t)row * 4096 + col] = f2bf(fmaxf(v, 0.f));
                        } else {
                            ((float*)Cptr)[(size_t)row * 2048 + col] = v;
                        }
                    }
            }
#undef STAGE_A
#undef STAGE_B
#undef DSREAD_A
#undef DSREAD_B
#undef MFMA_Q
#undef WAIT_VM
#undef WAIT_LGKM0
#undef BAR
}

// ---------------------------------------------------------------------------
extern "C" void kernel_launch(void* const* d_in, const int* in_sizes, int n_in,
                              void* d_out, int out_size, void* d_ws, size_t ws_size,
                              hipStream_t stream) {
    const float* x        = (const float*)d_in[0];
    const float* W_up     = (const float*)d_in[1];
    const float* W_down   = (const float*)d_in[2];
    // d_in[3] = W_gate: unused (softmax over top-k sums to 1 -> gating no-op)
    const float* W_expert = (const float*)d_in[4];

    // Workspace (bf16 as u16):
    //   A_big [16384][4096]: cols 0..2047 = h (GEMM1 output), 2048..4095 = x
    //   B_big [2048][4096] : cols 0..2047 = W_down, 2048..4095 = W_expert^T
    //   W_up_bf [2048][2048]
    u16* Abig = (u16*)d_ws;
    u16* Bbig = Abig + (size_t)MTOT * 4096;
    u16* Wup  = Bbig + (size_t)DIM * 4096;

    cvt_pack<<<2048, 256, 0, stream>>>(x, Abig, (long)MTOT * DIM / 4, 4096, 2048);
    cvt_pack<<<1024, 256, 0, stream>>>(W_up, Wup, (long)DIM * DIM / 4, 2048, 0);
    cvt_pack<<<1024, 256, 0, stream>>>(W_down, Bbig, (long)DIM * DIM / 4, 4096, 0);
    cvt_transpose<<<4096, 256, 0, stream>>>(W_expert, Bbig);

    // GEMM1: h = relu(x @ W_up^T) -> bf16 into A_big left half
    gemm256<0><<<512, 512, 0, stream>>>(Abig + 2048, Wup, Abig, 4096, 2048, 2048);
    // GEMM2: out = A_big @ B_big^T = h @ W_down^T + x @ W_expert (fp32)
    gemm256<1><<<512, 512, 0, stream>>>(Abig, Bbig, d_out, 4096, 4096, 4096);
}